// Round 15
// baseline (281.709 us; speedup 1.0000x reference)
//
#include <hip/hip_runtime.h>
#include <hip/hip_bf16.h>
#include <math.h>

// ---------------------------------------------------------------------------
// DualHeadGAT R15: R12 structure (best, 249.5us) with K3 occupancy fix:
//  - gemm1 half-waves (J=8, 2 waves per 16-row tile) -> kernel VGPR ~64
//    (was 88) so co-launched scatter runs at ~8 waves/SIMD.
//  - scan also emits cursor[i]=rowptr[i]+deg[i]; scatter uses
//    atomicSub(cursor)-1 (drops the dependent rowptr[d] load per edge).
//  - scatter blocks dispatched before gemm blocks.
//  - 7 dispatches: memset, fused_front, scan, scatter+gemm1, agg1, gemm2,
//    agg2. Aggregates/gemm2 identical to R12.
// N=50000, IN=128, E=800000. f32 in/out, int32 edges.
// ---------------------------------------------------------------------------

#define LRELU_SLOPE 0.2f

typedef __attribute__((ext_vector_type(8))) short short8;   // 8 bf16 = 4 VGPR
typedef __attribute__((ext_vector_type(4))) float f32x4;

__device__ inline ushort f2bf(float f) {            // RNE f32 -> bf16
    uint u = __float_as_uint(f);
    return (ushort)((u + 0x7FFFu + ((u >> 16) & 1u)) >> 16);
}
__device__ inline float bf2f(ushort u) {
    return __uint_as_float(((uint)u) << 16);
}

// ------- pre-fragment W[K][16J] (f32, row-major) into MFMA B-frag order ----
__device__ inline void prefrag_one(const float* __restrict__ W,
                                   ushort* __restrict__ out,
                                   int tid, int T, int ldn)
{
    int l = tid & 63, jt = tid >> 6;
    int t = jt % T, j = jt / T;
    int n = j * 16 + (l & 15);
    int k0 = t * 32 + (l >> 4) * 8;
    ushort o[8];
    #pragma unroll
    for (int b = 0; b < 8; ++b) o[b] = f2bf(W[(size_t)(k0 + b) * ldn + n]);
    *(short8*)(out + (size_t)tid * 8) = *(short8*)o;
}

// ---- K1: degree hist + x conversion + weight prefrags, one launch ---------
__global__ __launch_bounds__(256)
void fused_front(const float* __restrict__ x, ushort* __restrict__ xbf,
                 const float* __restrict__ W1, const float* __restrict__ W2,
                 ushort* __restrict__ o1, ushort* __restrict__ o2,
                 const int* __restrict__ edst, int* __restrict__ deg,
                 int nconv4, int E)
{
    int tid = blockIdx.x * blockDim.x + threadIdx.x;
    if (tid < nconv4) {                  // x f32 -> bf16, 4 elems/thread
        int i = tid << 2;
        float4 v = *(const float4*)(x + i);
        ushort4 o;
        o.x = f2bf(v.x); o.y = f2bf(v.y); o.z = f2bf(v.z); o.w = f2bf(v.w);
        *(ushort4*)(xbf + i) = o;
        return;
    }
    int t = tid - nconv4;
    if (t < 16 * 4 * 64) { prefrag_one(W1, o1, t, 4, 256); return; }
    t -= 16 * 4 * 64;
    if (t < 4 * 8 * 64)  { prefrag_one(W2, o2, t, 8, 64); return; }
    t -= 4 * 8 * 64;
    int i = t << 2;                      // degree histogram, 4 edges/thread
    if (i + 3 < E) {
        int4 v = *(const int4*)(edst + i);
        atomicAdd(&deg[v.x], 1); atomicAdd(&deg[v.y], 1);
        atomicAdd(&deg[v.z], 1); atomicAdd(&deg[v.w], 1);
    } else {
        for (; i < E; ++i) atomicAdd(&deg[edst[i]], 1);
    }
}

// ---------------- single-block exclusive scan (2 barriers) -----------------
// also emits cursor[i] = rowptr[i] + deg[i] (= exclusive end) for scatter.
__global__ __launch_bounds__(1024)
void scan_rowptr(const int* __restrict__ deg, int* __restrict__ rowptr,
                 int* __restrict__ cursor, int N)
{
    __shared__ int wsums[16];
    const int tid = threadIdx.x, lane = tid & 63, wid = tid >> 6;
    const int N4 = N >> 2;              // int4 count (N % 4 == 0)
    const int b4 = tid * 13;            // 13 int4 = 52 elems per thread
    int tsum = 0;
    #pragma unroll
    for (int k = 0; k < 13; ++k) {
        int i4 = b4 + k;
        if (i4 < N4) {
            int4 v = ((const int4*)deg)[i4];
            tsum += (v.x + v.y) + (v.z + v.w);
        }
    }
    int sc = tsum;                      // inclusive wave scan
    #pragma unroll
    for (int off = 1; off < 64; off <<= 1) {
        int t = __shfl_up(sc, off);
        if (lane >= off) sc += t;
    }
    if (lane == 63) wsums[wid] = sc;
    __syncthreads();
    if (wid == 0) {
        int wv = (lane < 16) ? wsums[lane] : 0;
        #pragma unroll
        for (int off = 1; off < 16; off <<= 1) {
            int t = __shfl_up(wv, off);
            if (lane >= off) wv += t;
        }
        if (lane < 16) wsums[lane] = wv;
    }
    __syncthreads();
    int run = (wid ? wsums[wid - 1] : 0) + sc - tsum;   // exclusive start
    #pragma unroll
    for (int k = 0; k < 13; ++k) {
        int i4 = b4 + k;
        if (i4 < N4) {
            int4 v = ((const int4*)deg)[i4];
            int4 o, c;
            o.x = run;        c.x = run + v.x;
            o.y = c.x;        c.y = c.x + v.y;
            o.z = c.y;        c.z = c.y + v.z;
            o.w = c.z;        c.w = c.z + v.w;
            ((int4*)rowptr)[i4] = o;
            ((int4*)cursor)[i4] = c;
            run = c.w;
        }
    }
    if (tid == 1023) rowptr[N] = run;   // all data precedes thread 1023
}

// ---- K3: scatter (first) + gemm1 (half-waves, low VGPR) in one launch -----
// gemm part: 2 waves per 16-row tile; wave handles 8 j-blocks (2 heads).
__global__ __launch_bounds__(256)
void scatter_gemm1(const ushort* __restrict__ A, const ushort* __restrict__ Bf,
                   ushort* __restrict__ Cbf, const float* __restrict__ attS,
                   const float* __restrict__ attD, float* __restrict__ as_,
                   float* __restrict__ ad_, int M, int scatterBlocks,
                   const int* __restrict__ esrc, const int* __restrict__ edst,
                   int* __restrict__ cursor, int* __restrict__ csr_src, int E)
{
    if ((int)blockIdx.x < scatterBlocks) {
        int i = blockIdx.x * blockDim.x + threadIdx.x;
        if (i >= E) return;
        int s = esrc[i], d = edst[i];
        int pos = atomicSub(&cursor[d], 1) - 1;
        csr_src[pos] = s;
        return;
    }
    const int wv = (blockIdx.x - scatterBlocks) * 4 + (threadIdx.x >> 6);
    const int rowTile = wv >> 1;
    const int half = wv & 1;             // column half (heads 0-1 / 2-3)
    const int base = rowTile * 16;
    if (base >= M) return;
    const int l = threadIdx.x & 63;
    const int lm = l & 15, lg = l >> 4;

    short8 a[4];
    const ushort* ap = A + (size_t)(base + lm) * 128 + lg * 8;
    #pragma unroll
    for (int t = 0; t < 4; ++t) a[t] = *(const short8*)(ap + t * 32);

    f32x4 acc[8];
    #pragma unroll
    for (int j = 0; j < 8; ++j) acc[j] = (f32x4){0.f, 0.f, 0.f, 0.f};

    const ushort* bp = Bf + (size_t)l * 8;
    #pragma unroll
    for (int j = 0; j < 8; ++j) {
        const int jg = half * 8 + j;
        #pragma unroll
        for (int t = 0; t < 4; ++t) {
            short8 b = *(const short8*)(bp + (size_t)(jg * 4 + t) * 512);
            acc[j] = __builtin_amdgcn_mfma_f32_16x16x32_bf16(a[t], b, acc[j], 0, 0, 0);
        }
    }

    float sp[2][4], dp[2][4];
    #pragma unroll
    for (int h = 0; h < 2; ++h)
        #pragma unroll
        for (int r = 0; r < 4; ++r) { sp[h][r] = 0.f; dp[h][r] = 0.f; }

    #pragma unroll
    for (int j = 0; j < 8; ++j) {
        const int h = j >> 2;            // head within this half
        const int hg = half * 2 + h;     // global head
        float ws = attS[hg * 64 + (j & 3) * 16 + lm];
        float wd = attD[hg * 64 + (j & 3) * 16 + lm];
        #pragma unroll
        for (int r = 0; r < 4; ++r) {
            int row = base + lg * 4 + r;
            Cbf[(size_t)row * 256 + (half * 8 + j) * 16 + lm] = f2bf(acc[j][r]);
            sp[h][r] = fmaf(acc[j][r], ws, sp[h][r]);
            dp[h][r] = fmaf(acc[j][r], wd, dp[h][r]);
        }
    }
    #pragma unroll
    for (int h = 0; h < 2; ++h)
        #pragma unroll
        for (int r = 0; r < 4; ++r) {
            float s = sp[h][r], d = dp[h][r];
            s += __shfl_xor(s, 1); d += __shfl_xor(d, 1);
            s += __shfl_xor(s, 2); d += __shfl_xor(d, 2);
            s += __shfl_xor(s, 4); d += __shfl_xor(d, 4);
            s += __shfl_xor(s, 8); d += __shfl_xor(d, 8);
            if (lm == 0) {
                int row = base + lg * 4 + r;
                as_[row * 4 + half * 2 + h] = s;
                ad_[row * 4 + half * 2 + h] = d;
            }
        }
}

// ---------------- gemm2 (standalone, R12 form) -----------------------------
template<int J, int T, int H>
__global__ __launch_bounds__(256)
void gemm_mfma(const ushort* __restrict__ A, const ushort* __restrict__ Bf,
               ushort* __restrict__ Cbf, const float* __restrict__ attS,
               const float* __restrict__ attD, float* __restrict__ as_,
               float* __restrict__ ad_, int M)
{
    constexpr int K = 32 * T;
    constexpr int NN = 16 * J;
    const int l = threadIdx.x & 63;
    const int wid = blockIdx.x * (blockDim.x >> 6) + (threadIdx.x >> 6);
    const int base = wid * 16;
    if (base >= M) return;
    const int lm = l & 15, lg = l >> 4;

    short8 a[T];
    const ushort* ap = A + (size_t)(base + lm) * K + lg * 8;
    #pragma unroll
    for (int t = 0; t < T; ++t) a[t] = *(const short8*)(ap + t * 32);

    f32x4 acc[J];
    #pragma unroll
    for (int j = 0; j < J; ++j) acc[j] = (f32x4){0.f, 0.f, 0.f, 0.f};

    const ushort* bp = Bf + (size_t)l * 8;
    #pragma unroll
    for (int j = 0; j < J; ++j)
        #pragma unroll
        for (int t = 0; t < T; ++t) {
            short8 b = *(const short8*)(bp + (size_t)(j * T + t) * 512);
            acc[j] = __builtin_amdgcn_mfma_f32_16x16x32_bf16(a[t], b, acc[j], 0, 0, 0);
        }

    float sp[H][4], dp[H][4];
    #pragma unroll
    for (int h = 0; h < H; ++h)
        #pragma unroll
        for (int r = 0; r < 4; ++r) { sp[h][r] = 0.f; dp[h][r] = 0.f; }

    #pragma unroll
    for (int j = 0; j < J; ++j) {
        const int h = j / (J / H);
        const int coff = (j % (J / H)) * 16 + lm;
        float ws = attS[h * 64 + coff];
        float wd = attD[h * 64 + coff];
        #pragma unroll
        for (int r = 0; r < 4; ++r) {
            int row = base + lg * 4 + r;
            Cbf[(size_t)row * NN + j * 16 + lm] = f2bf(acc[j][r]);
            sp[h][r] = fmaf(acc[j][r], ws, sp[h][r]);
            dp[h][r] = fmaf(acc[j][r], wd, dp[h][r]);
        }
    }
    #pragma unroll
    for (int h = 0; h < H; ++h)
        #pragma unroll
        for (int r = 0; r < 4; ++r) {
            float s = sp[h][r], d = dp[h][r];
            s += __shfl_xor(s, 1); d += __shfl_xor(d, 1);
            s += __shfl_xor(s, 2); d += __shfl_xor(d, 2);
            s += __shfl_xor(s, 4); d += __shfl_xor(d, 4);
            s += __shfl_xor(s, 8); d += __shfl_xor(d, 8);
            if (lm == 0) {
                int row = base + lg * 4 + r;
                as_[row * H + h] = s;
                ad_[row * H + h] = d;
            }
        }
}

// -------- layer-1 aggregation (R12 form): 4x unroll; shfl p-dedup ----------
__global__ __launch_bounds__(256)
void aggregate_l1(const int* __restrict__ rowptr, const int* __restrict__ csr_src,
                  const ushort* __restrict__ h1, const float* __restrict__ as_,
                  const float* __restrict__ ad_, const float* __restrict__ bias,
                  ushort* __restrict__ outbf, int N)
{
    int w = (blockIdx.x * blockDim.x + threadIdx.x) >> 6;
    int lane = threadIdx.x & 63;
    if (w >= N) return;
    const int head = lane >> 4;          // 4 heads x 16 lanes
    const int c0 = lane << 2;            // ushort4 per lane
    const int my = lane & 3;             // this lane's coef slot
    const int hb = lane & 48;            // head-group base lane
    const float ad = ad_[w * 4 + head];
    float4 acc;
    float dsum;

    {   // implicit self-loop
        float el = as_[w * 4 + head] + ad;
        el = el > 0.f ? el : LRELU_SLOPE * el;
        float p = __expf(el);
        ushort4 u = *(const ushort4*)(h1 + (size_t)w * 256 + c0);
        acc.x = p * bf2f(u.x); acc.y = p * bf2f(u.y);
        acc.z = p * bf2f(u.z); acc.w = p * bf2f(u.w);
        dsum = p;
    }

    int e = rowptr[w];
    const int e1 = rowptr[w + 1];
    for (; e + 3 < e1; e += 4) {         // 4 independent gathers in flight
        int s0 = csr_src[e],     s1 = csr_src[e + 1];
        int s2 = csr_src[e + 2], s3 = csr_src[e + 3];
        ushort4 u0 = *(const ushort4*)(h1 + (size_t)s0 * 256 + c0);
        ushort4 u1 = *(const ushort4*)(h1 + (size_t)s1 * 256 + c0);
        ushort4 u2 = *(const ushort4*)(h1 + (size_t)s2 * 256 + c0);
        ushort4 u3 = *(const ushort4*)(h1 + (size_t)s3 * 256 + c0);
        int ms = s0;
        ms = (my == 1) ? s1 : ms;
        ms = (my == 2) ? s2 : ms;
        ms = (my == 3) ? s3 : ms;
        float ev = as_[ms * 4 + head] + ad;
        ev = ev > 0.f ? ev : LRELU_SLOPE * ev;
        float pl = __expf(ev);
        float p0 = __shfl(pl, hb | 0);
        float p1 = __shfl(pl, hb | 1);
        float p2 = __shfl(pl, hb | 2);
        float p3 = __shfl(pl, hb | 3);
        acc.x = fmaf(p0, bf2f(u0.x), acc.x); acc.y = fmaf(p0, bf2f(u0.y), acc.y);
        acc.z = fmaf(p0, bf2f(u0.z), acc.z); acc.w = fmaf(p0, bf2f(u0.w), acc.w);
        acc.x = fmaf(p1, bf2f(u1.x), acc.x); acc.y = fmaf(p1, bf2f(u1.y), acc.y);
        acc.z = fmaf(p1, bf2f(u1.z), acc.z); acc.w = fmaf(p1, bf2f(u1.w), acc.w);
        acc.x = fmaf(p2, bf2f(u2.x), acc.x); acc.y = fmaf(p2, bf2f(u2.y), acc.y);
        acc.z = fmaf(p2, bf2f(u2.z), acc.z); acc.w = fmaf(p2, bf2f(u2.w), acc.w);
        acc.x = fmaf(p3, bf2f(u3.x), acc.x); acc.y = fmaf(p3, bf2f(u3.y), acc.y);
        acc.z = fmaf(p3, bf2f(u3.z), acc.z); acc.w = fmaf(p3, bf2f(u3.w), acc.w);
        dsum += (p0 + p1) + (p2 + p3);
    }
    for (; e < e1; ++e) {
        int s0 = csr_src[e];
        float e0 = as_[s0 * 4 + head] + ad;
        e0 = e0 > 0.f ? e0 : LRELU_SLOPE * e0;
        float p0 = __expf(e0);
        ushort4 u0 = *(const ushort4*)(h1 + (size_t)s0 * 256 + c0);
        acc.x = fmaf(p0, bf2f(u0.x), acc.x); acc.y = fmaf(p0, bf2f(u0.y), acc.y);
        acc.z = fmaf(p0, bf2f(u0.z), acc.z); acc.w = fmaf(p0, bf2f(u0.w), acc.w);
        dsum += p0;
    }
    const float inv = 1.f / (dsum + 1e-16f);
    const float4 b = *(const float4*)(bias + c0);
    float ox = acc.x * inv + b.x; ox = ox > 0.f ? ox : expm1f(ox);
    float oy = acc.y * inv + b.y; oy = oy > 0.f ? oy : expm1f(oy);
    float oz = acc.z * inv + b.z; oz = oz > 0.f ? oz : expm1f(oz);
    float ow = acc.w * inv + b.w; ow = ow > 0.f ? ow : expm1f(ow);
    ushort4 o;
    o.x = f2bf(ox); o.y = f2bf(oy); o.z = f2bf(oz); o.w = f2bf(ow);
    *(ushort4*)(outbf + (size_t)w * 256 + c0) = o;
}

// -------- layer-2 aggregation + scoring head (R12 form) --------------------
__global__ __launch_bounds__(256)
void aggregate_l2(const int* __restrict__ rowptr, const int* __restrict__ csr_src,
                  const ushort* __restrict__ h2, const float* __restrict__ as_,
                  const float* __restrict__ ad_, const float* __restrict__ b2,
                  const float* __restrict__ Wsv, const float* __restrict__ bs,
                  float* __restrict__ hout, float* __restrict__ scores, int N)
{
    int w = (blockIdx.x * blockDim.x + threadIdx.x) >> 6;
    int lane = threadIdx.x & 63;
    if (w >= N) return;
    const int my = lane & 3;
    const float ad = ad_[w];
    float acc, dsum;
    {   // implicit self-loop
        float el = as_[w] + ad;
        el = el > 0.f ? el : LRELU_SLOPE * el;
        float p = __expf(el);
        acc = p * bf2f(h2[(size_t)w * 64 + lane]);
        dsum = p;
    }
    int e = rowptr[w];
    const int e1 = rowptr[w + 1];
    for (; e + 3 < e1; e += 4) {
        int s0 = csr_src[e],     s1 = csr_src[e + 1];
        int s2 = csr_src[e + 2], s3 = csr_src[e + 3];
        ushort f0 = h2[(size_t)s0 * 64 + lane];
        ushort f1 = h2[(size_t)s1 * 64 + lane];
        ushort f2 = h2[(size_t)s2 * 64 + lane];
        ushort f3 = h2[(size_t)s3 * 64 + lane];
        int ms = s0;
        ms = (my == 1) ? s1 : ms;
        ms = (my == 2) ? s2 : ms;
        ms = (my == 3) ? s3 : ms;
        float ev = as_[ms] + ad;
        ev = ev > 0.f ? ev : LRELU_SLOPE * ev;
        float pl = __expf(ev);
        float p0 = __shfl(pl, 0);
        float p1 = __shfl(pl, 1);
        float p2 = __shfl(pl, 2);
        float p3 = __shfl(pl, 3);
        acc = fmaf(p0, bf2f(f0), acc);
        acc = fmaf(p1, bf2f(f1), acc);
        acc = fmaf(p2, bf2f(f2), acc);
        acc = fmaf(p3, bf2f(f3), acc);
        dsum += (p0 + p1) + (p2 + p3);
    }
    for (; e < e1; ++e) {
        int s0 = csr_src[e];
        float e0 = as_[s0] + ad;
        e0 = e0 > 0.f ? e0 : LRELU_SLOPE * e0;
        float p0 = __expf(e0);
        acc = fmaf(p0, bf2f(h2[(size_t)s0 * 64 + lane]), acc);
        dsum += p0;
    }
    float v = acc / (dsum + 1e-16f) + b2[lane];
    v = v > 0.f ? v : expm1f(v);
    hout[(size_t)w * 64 + lane] = v;
    float sc = v * Wsv[lane];
    #pragma unroll
    for (int off = 32; off; off >>= 1) sc += __shfl_down(sc, off);
    if (lane == 0) scores[w] = sc + bs[0];
}

// ---------------------------------------------------------------------------
extern "C" void kernel_launch(void* const* d_in, const int* in_sizes, int n_in,
                              void* d_out, int out_size, void* d_ws, size_t ws_size,
                              hipStream_t stream)
{
    const float* x    = (const float*)d_in[0];
    const int*   ei   = (const int*)d_in[1];
    const float* W1   = (const float*)d_in[2];
    const float* as1w = (const float*)d_in[3];
    const float* ad1w = (const float*)d_in[4];
    const float* b1   = (const float*)d_in[5];
    const float* W2   = (const float*)d_in[6];
    const float* as2w = (const float*)d_in[7];
    const float* ad2w = (const float*)d_in[8];
    const float* b2   = (const float*)d_in[9];
    const float* Ws   = (const float*)d_in[10];
    const float* bs   = (const float*)d_in[11];

    const int N  = in_sizes[0] / 128;   // 50000
    const int E  = in_sizes[1] / 2;     // 800000
    const int* esrc = ei;
    const int* edst = ei + E;

    // ---- workspace layout (16B-aligned chunks) ----
    ushort* h1bf  = (ushort*)d_ws;                       // N*256 bf16
    ushort* hl1bf = h1bf + (size_t)N * 256;              // N*256 bf16
    ushort* h2bf  = hl1bf + (size_t)N * 256;             // N*64 bf16
    ushort* xbf   = h2bf + (size_t)N * 64;               // N*128 bf16
    ushort* bfr1  = xbf + (size_t)N * 128;               // 32768
    ushort* bfr2  = bfr1 + 32768;                        // 16384
    float*  as1   = (float*)(bfr2 + 16384);              // N*4
    float*  ad1   = as1 + (size_t)N * 4;                 // N*4
    float*  as2   = ad1 + (size_t)N * 4;                 // N
    float*  ad2   = as2 + N;                             // N
    int*    deg    = (int*)(ad2 + N);                    // N
    int*    cursor = deg + N;                            // N
    int*    rowptr = cursor + N;                         // N+1 (+pad)
    int*    csr_src= rowptr + N + 4;                     // E

    float* hout   = (float*)d_out;                       // N*64
    float* scores = hout + (size_t)N * 64;               // N

    // ---------------- K0: zero deg ----------------
    hipMemsetAsync(deg, 0, (size_t)N * sizeof(int), stream);

    // ---------------- K1: hist + conv + prefrags ----------------
    const int nconv4 = N * 128 / 4;                      // 1,600,000
    const int nfrag  = 16 * 4 * 64 + 4 * 8 * 64;         // 6,144
    const int nhist  = (E + 3) / 4;                      // 200,000
    fused_front<<<(nconv4 + nfrag + nhist + 255) / 256, 256, 0, stream>>>(
        x, xbf, W1, W2, bfr1, bfr2, edst, deg, nconv4, E);

    // ---------------- K2: rowptr + cursor scan ----------------
    scan_rowptr<<<1, 1024, 0, stream>>>(deg, rowptr, cursor, N);

    // ---------------- K3: scatter (first) + gemm1 (half-waves) ----------
    const int scatterBlocks = (E + 255) / 256;           // 3125
    const int gemmBlocks    = (N / 16 * 2 + 3) / 4;      // 1563
    scatter_gemm1<<<scatterBlocks + gemmBlocks, 256, 0, stream>>>(
        xbf, bfr1, h1bf, as1w, ad1w, as1, ad1, N, scatterBlocks,
        esrc, edst, cursor, csr_src, E);

    // ---------------- K4: agg1 ----------------
    aggregate_l1<<<((size_t)N * 64 + 255) / 256, 256, 0, stream>>>(
        rowptr, csr_src, h1bf, as1, ad1, b1, hl1bf, N);

    // ---------------- K5: gemm2 ----------------
    gemm_mfma<4, 8, 1><<<(N / 16 + 3) / 4, 256, 0, stream>>>(
        hl1bf, bfr2, h2bf, as2w, ad2w, as2, ad2, N);

    // ---------------- K6: agg2 + scoring head ----------------
    aggregate_l2<<<((size_t)N * 64 + 255) / 256, 256, 0, stream>>>(
        rowptr, csr_src, h2bf, as2, ad2, b2, Ws, bs, hout, scores, N);
}

// Round 16
// 226.934 us; speedup vs baseline: 1.2414x; 1.2414x over previous
//
#include <hip/hip_runtime.h>
#include <hip/hip_bf16.h>
#include <math.h>

// ---------------------------------------------------------------------------
// DualHeadGAT R16: R12 structure (best, 249.5us) + atomic-free scatter:
//  - K1's degree histogram captures atomicAdd return value as order[i]
//    (edge's within-node rank) -- the atomic cost is paid in K1 where it
//    overlaps the 38MB x-conversion.
//  - K3's scatter becomes pure streaming: csr_src[rowptr[d]+order[i]]=s.
//    No atomic round-trip in the critical path (R13/R15 showed the atomic
//    chain + contention was the scatter's cost, not occupancy).
//  - 7 dispatches: memset, fused_front, scan, gemm1+scatter, agg1, gemm2,
//    agg2. Aggregates/gemms identical to R12.
// N=50000, IN=128, E=800000. f32 in/out, int32 edges.
// ---------------------------------------------------------------------------

#define LRELU_SLOPE 0.2f

typedef __attribute__((ext_vector_type(8))) short short8;   // 8 bf16 = 4 VGPR
typedef __attribute__((ext_vector_type(4))) float f32x4;

__device__ inline ushort f2bf(float f) {            // RNE f32 -> bf16
    uint u = __float_as_uint(f);
    return (ushort)((u + 0x7FFFu + ((u >> 16) & 1u)) >> 16);
}
__device__ inline float bf2f(ushort u) {
    return __uint_as_float(((uint)u) << 16);
}

// ------- pre-fragment W[K][16J] (f32, row-major) into MFMA B-frag order ----
__device__ inline void prefrag_one(const float* __restrict__ W,
                                   ushort* __restrict__ out,
                                   int tid, int T, int ldn)
{
    int l = tid & 63, jt = tid >> 6;
    int t = jt % T, j = jt / T;
    int n = j * 16 + (l & 15);
    int k0 = t * 32 + (l >> 4) * 8;
    ushort o[8];
    #pragma unroll
    for (int b = 0; b < 8; ++b) o[b] = f2bf(W[(size_t)(k0 + b) * ldn + n]);
    *(short8*)(out + (size_t)tid * 8) = *(short8*)o;
}

// ---- K1: degree hist (captures order) + x conversion + weight prefrags ----
__global__ __launch_bounds__(256)
void fused_front(const float* __restrict__ x, ushort* __restrict__ xbf,
                 const float* __restrict__ W1, const float* __restrict__ W2,
                 ushort* __restrict__ o1, ushort* __restrict__ o2,
                 const int* __restrict__ edst, int* __restrict__ deg,
                 int* __restrict__ order, int nconv4, int E)
{
    int tid = blockIdx.x * blockDim.x + threadIdx.x;
    if (tid < nconv4) {                  // x f32 -> bf16, 4 elems/thread
        int i = tid << 2;
        float4 v = *(const float4*)(x + i);
        ushort4 o;
        o.x = f2bf(v.x); o.y = f2bf(v.y); o.z = f2bf(v.z); o.w = f2bf(v.w);
        *(ushort4*)(xbf + i) = o;
        return;
    }
    int t = tid - nconv4;
    if (t < 16 * 4 * 64) { prefrag_one(W1, o1, t, 4, 256); return; }
    t -= 16 * 4 * 64;
    if (t < 4 * 8 * 64)  { prefrag_one(W2, o2, t, 8, 64); return; }
    t -= 4 * 8 * 64;
    int i = t << 2;                      // degree histogram, 4 edges/thread
    if (i + 3 < E) {
        int4 v = *(const int4*)(edst + i);
        int4 o;
        o.x = atomicAdd(&deg[v.x], 1);
        o.y = atomicAdd(&deg[v.y], 1);
        o.z = atomicAdd(&deg[v.z], 1);
        o.w = atomicAdd(&deg[v.w], 1);
        *(int4*)(order + i) = o;
    } else {
        for (; i < E; ++i) order[i] = atomicAdd(&deg[edst[i]], 1);
    }
}

// ---------------- single-block exclusive scan (2 barriers) -----------------
__global__ __launch_bounds__(1024)
void scan_rowptr(const int* __restrict__ deg, int* __restrict__ rowptr, int N)
{
    __shared__ int wsums[16];
    const int tid = threadIdx.x, lane = tid & 63, wid = tid >> 6;
    const int N4 = N >> 2;              // int4 count (N % 4 == 0)
    const int b4 = tid * 13;            // 13 int4 = 52 elems per thread
    int tsum = 0;
    #pragma unroll
    for (int k = 0; k < 13; ++k) {
        int i4 = b4 + k;
        if (i4 < N4) {
            int4 v = ((const int4*)deg)[i4];
            tsum += (v.x + v.y) + (v.z + v.w);
        }
    }
    int sc = tsum;                      // inclusive wave scan
    #pragma unroll
    for (int off = 1; off < 64; off <<= 1) {
        int t = __shfl_up(sc, off);
        if (lane >= off) sc += t;
    }
    if (lane == 63) wsums[wid] = sc;
    __syncthreads();
    if (wid == 0) {
        int wv = (lane < 16) ? wsums[lane] : 0;
        #pragma unroll
        for (int off = 1; off < 16; off <<= 1) {
            int t = __shfl_up(wv, off);
            if (lane >= off) wv += t;
        }
        if (lane < 16) wsums[lane] = wv;
    }
    __syncthreads();
    int run = (wid ? wsums[wid - 1] : 0) + sc - tsum;   // exclusive start
    #pragma unroll
    for (int k = 0; k < 13; ++k) {
        int i4 = b4 + k;
        if (i4 < N4) {
            int4 v = ((const int4*)deg)[i4];
            int4 o;
            o.x = run; o.y = run + v.x; o.z = o.y + v.y; o.w = o.z + v.z;
            ((int4*)rowptr)[i4] = o;
            run += (v.x + v.y) + (v.z + v.w);
        }
    }
    if (tid == 1023) rowptr[N] = run;   // all data precedes thread 1023
}

// ---------------- MFMA GEMM body (device fn) -------------------------------
template<int J, int T, int H>
__device__ inline void gemm_body(int wid, const ushort* __restrict__ A,
                                 const ushort* __restrict__ Bf,
                                 ushort* __restrict__ Cbf,
                                 const float* __restrict__ attS,
                                 const float* __restrict__ attD,
                                 float* __restrict__ as_,
                                 float* __restrict__ ad_, int M)
{
    constexpr int K = 32 * T;
    constexpr int NN = 16 * J;
    const int l = threadIdx.x & 63;
    const int base = wid * 16;
    if (base >= M) return;
    const int lm = l & 15, lg = l >> 4;

    short8 a[T];
    const ushort* ap = A + (size_t)(base + lm) * K + lg * 8;
    #pragma unroll
    for (int t = 0; t < T; ++t) a[t] = *(const short8*)(ap + t * 32);

    f32x4 acc[J];
    #pragma unroll
    for (int j = 0; j < J; ++j) acc[j] = (f32x4){0.f, 0.f, 0.f, 0.f};

    const ushort* bp = Bf + (size_t)l * 8;
    #pragma unroll
    for (int j = 0; j < J; ++j)
        #pragma unroll
        for (int t = 0; t < T; ++t) {
            short8 b = *(const short8*)(bp + (size_t)(j * T + t) * 512);
            acc[j] = __builtin_amdgcn_mfma_f32_16x16x32_bf16(a[t], b, acc[j], 0, 0, 0);
        }

    float sp[H][4], dp[H][4];
    #pragma unroll
    for (int h = 0; h < H; ++h)
        #pragma unroll
        for (int r = 0; r < 4; ++r) { sp[h][r] = 0.f; dp[h][r] = 0.f; }

    #pragma unroll
    for (int j = 0; j < J; ++j) {
        const int h = j / (J / H);
        const int coff = (j % (J / H)) * 16 + lm;
        float ws = attS[h * 64 + coff];
        float wd = attD[h * 64 + coff];
        #pragma unroll
        for (int r = 0; r < 4; ++r) {
            int row = base + lg * 4 + r;
            Cbf[(size_t)row * NN + j * 16 + lm] = f2bf(acc[j][r]);
            sp[h][r] = fmaf(acc[j][r], ws, sp[h][r]);
            dp[h][r] = fmaf(acc[j][r], wd, dp[h][r]);
        }
    }
    #pragma unroll
    for (int h = 0; h < H; ++h)
        #pragma unroll
        for (int r = 0; r < 4; ++r) {
            float s = sp[h][r], d = dp[h][r];
            s += __shfl_xor(s, 1); d += __shfl_xor(d, 1);
            s += __shfl_xor(s, 2); d += __shfl_xor(d, 2);
            s += __shfl_xor(s, 4); d += __shfl_xor(d, 4);
            s += __shfl_xor(s, 8); d += __shfl_xor(d, 8);
            if (lm == 0) {
                int row = base + lg * 4 + r;
                as_[row * H + h] = s;
                ad_[row * H + h] = d;
            }
        }
}

// ---- K3: gemm1 + atomic-free scatter in one launch ------------------------
__global__ __launch_bounds__(256)
void scatter_gemm1(const ushort* __restrict__ A, const ushort* __restrict__ Bf,
                   ushort* __restrict__ Cbf, const float* __restrict__ attS,
                   const float* __restrict__ attD, float* __restrict__ as_,
                   float* __restrict__ ad_, int M, int gemmBlocks,
                   const int* __restrict__ esrc, const int* __restrict__ edst,
                   const int* __restrict__ rowptr, const int* __restrict__ order,
                   int* __restrict__ csr_src, int E)
{
    if ((int)blockIdx.x < gemmBlocks) {
        int wid = blockIdx.x * (blockDim.x >> 6) + (threadIdx.x >> 6);
        gemm_body<16, 4, 4>(wid, A, Bf, Cbf, attS, attD, as_, ad_, M);
        return;
    }
    // scatter: pure streaming placement, no atomics in the critical path
    int i = (blockIdx.x - gemmBlocks) * blockDim.x + threadIdx.x;
    if (i >= E) return;
    csr_src[rowptr[edst[i]] + order[i]] = esrc[i];
}

// ---------------- gemm2 (standalone) ---------------------------------------
template<int J, int T, int H>
__global__ __launch_bounds__(256)
void gemm_mfma(const ushort* __restrict__ A, const ushort* __restrict__ Bf,
               ushort* __restrict__ Cbf, const float* __restrict__ attS,
               const float* __restrict__ attD, float* __restrict__ as_,
               float* __restrict__ ad_, int M)
{
    int wid = blockIdx.x * (blockDim.x >> 6) + (threadIdx.x >> 6);
    gemm_body<J, T, H>(wid, A, Bf, Cbf, attS, attD, as_, ad_, M);
}

// -------- layer-1 aggregation (R12 form): 4x unroll; shfl p-dedup ----------
__global__ __launch_bounds__(256)
void aggregate_l1(const int* __restrict__ rowptr, const int* __restrict__ csr_src,
                  const ushort* __restrict__ h1, const float* __restrict__ as_,
                  const float* __restrict__ ad_, const float* __restrict__ bias,
                  ushort* __restrict__ outbf, int N)
{
    int w = (blockIdx.x * blockDim.x + threadIdx.x) >> 6;
    int lane = threadIdx.x & 63;
    if (w >= N) return;
    const int head = lane >> 4;          // 4 heads x 16 lanes
    const int c0 = lane << 2;            // ushort4 per lane
    const int my = lane & 3;             // this lane's coef slot
    const int hb = lane & 48;            // head-group base lane
    const float ad = ad_[w * 4 + head];
    float4 acc;
    float dsum;

    {   // implicit self-loop
        float el = as_[w * 4 + head] + ad;
        el = el > 0.f ? el : LRELU_SLOPE * el;
        float p = __expf(el);
        ushort4 u = *(const ushort4*)(h1 + (size_t)w * 256 + c0);
        acc.x = p * bf2f(u.x); acc.y = p * bf2f(u.y);
        acc.z = p * bf2f(u.z); acc.w = p * bf2f(u.w);
        dsum = p;
    }

    int e = rowptr[w];
    const int e1 = rowptr[w + 1];
    for (; e + 3 < e1; e += 4) {         // 4 independent gathers in flight
        int s0 = csr_src[e],     s1 = csr_src[e + 1];
        int s2 = csr_src[e + 2], s3 = csr_src[e + 3];
        ushort4 u0 = *(const ushort4*)(h1 + (size_t)s0 * 256 + c0);
        ushort4 u1 = *(const ushort4*)(h1 + (size_t)s1 * 256 + c0);
        ushort4 u2 = *(const ushort4*)(h1 + (size_t)s2 * 256 + c0);
        ushort4 u3 = *(const ushort4*)(h1 + (size_t)s3 * 256 + c0);
        int ms = s0;
        ms = (my == 1) ? s1 : ms;
        ms = (my == 2) ? s2 : ms;
        ms = (my == 3) ? s3 : ms;
        float ev = as_[ms * 4 + head] + ad;
        ev = ev > 0.f ? ev : LRELU_SLOPE * ev;
        float pl = __expf(ev);
        float p0 = __shfl(pl, hb | 0);
        float p1 = __shfl(pl, hb | 1);
        float p2 = __shfl(pl, hb | 2);
        float p3 = __shfl(pl, hb | 3);
        acc.x = fmaf(p0, bf2f(u0.x), acc.x); acc.y = fmaf(p0, bf2f(u0.y), acc.y);
        acc.z = fmaf(p0, bf2f(u0.z), acc.z); acc.w = fmaf(p0, bf2f(u0.w), acc.w);
        acc.x = fmaf(p1, bf2f(u1.x), acc.x); acc.y = fmaf(p1, bf2f(u1.y), acc.y);
        acc.z = fmaf(p1, bf2f(u1.z), acc.z); acc.w = fmaf(p1, bf2f(u1.w), acc.w);
        acc.x = fmaf(p2, bf2f(u2.x), acc.x); acc.y = fmaf(p2, bf2f(u2.y), acc.y);
        acc.z = fmaf(p2, bf2f(u2.z), acc.z); acc.w = fmaf(p2, bf2f(u2.w), acc.w);
        acc.x = fmaf(p3, bf2f(u3.x), acc.x); acc.y = fmaf(p3, bf2f(u3.y), acc.y);
        acc.z = fmaf(p3, bf2f(u3.z), acc.z); acc.w = fmaf(p3, bf2f(u3.w), acc.w);
        dsum += (p0 + p1) + (p2 + p3);
    }
    for (; e < e1; ++e) {
        int s0 = csr_src[e];
        float e0 = as_[s0 * 4 + head] + ad;
        e0 = e0 > 0.f ? e0 : LRELU_SLOPE * e0;
        float p0 = __expf(e0);
        ushort4 u0 = *(const ushort4*)(h1 + (size_t)s0 * 256 + c0);
        acc.x = fmaf(p0, bf2f(u0.x), acc.x); acc.y = fmaf(p0, bf2f(u0.y), acc.y);
        acc.z = fmaf(p0, bf2f(u0.z), acc.z); acc.w = fmaf(p0, bf2f(u0.w), acc.w);
        dsum += p0;
    }
    const float inv = 1.f / (dsum + 1e-16f);
    const float4 b = *(const float4*)(bias + c0);
    float ox = acc.x * inv + b.x; ox = ox > 0.f ? ox : expm1f(ox);
    float oy = acc.y * inv + b.y; oy = oy > 0.f ? oy : expm1f(oy);
    float oz = acc.z * inv + b.z; oz = oz > 0.f ? oz : expm1f(oz);
    float ow = acc.w * inv + b.w; ow = ow > 0.f ? ow : expm1f(ow);
    ushort4 o;
    o.x = f2bf(ox); o.y = f2bf(oy); o.z = f2bf(oz); o.w = f2bf(ow);
    *(ushort4*)(outbf + (size_t)w * 256 + c0) = o;
}

// -------- layer-2 aggregation + scoring head (R12 form) --------------------
__global__ __launch_bounds__(256)
void aggregate_l2(const int* __restrict__ rowptr, const int* __restrict__ csr_src,
                  const ushort* __restrict__ h2, const float* __restrict__ as_,
                  const float* __restrict__ ad_, const float* __restrict__ b2,
                  const float* __restrict__ Wsv, const float* __restrict__ bs,
                  float* __restrict__ hout, float* __restrict__ scores, int N)
{
    int w = (blockIdx.x * blockDim.x + threadIdx.x) >> 6;
    int lane = threadIdx.x & 63;
    if (w >= N) return;
    const int my = lane & 3;
    const float ad = ad_[w];
    float acc, dsum;
    {   // implicit self-loop
        float el = as_[w] + ad;
        el = el > 0.f ? el : LRELU_SLOPE * el;
        float p = __expf(el);
        acc = p * bf2f(h2[(size_t)w * 64 + lane]);
        dsum = p;
    }
    int e = rowptr[w];
    const int e1 = rowptr[w + 1];
    for (; e + 3 < e1; e += 4) {
        int s0 = csr_src[e],     s1 = csr_src[e + 1];
        int s2 = csr_src[e + 2], s3 = csr_src[e + 3];
        ushort f0 = h2[(size_t)s0 * 64 + lane];
        ushort f1 = h2[(size_t)s1 * 64 + lane];
        ushort f2 = h2[(size_t)s2 * 64 + lane];
        ushort f3 = h2[(size_t)s3 * 64 + lane];
        int ms = s0;
        ms = (my == 1) ? s1 : ms;
        ms = (my == 2) ? s2 : ms;
        ms = (my == 3) ? s3 : ms;
        float ev = as_[ms] + ad;
        ev = ev > 0.f ? ev : LRELU_SLOPE * ev;
        float pl = __expf(ev);
        float p0 = __shfl(pl, 0);
        float p1 = __shfl(pl, 1);
        float p2 = __shfl(pl, 2);
        float p3 = __shfl(pl, 3);
        acc = fmaf(p0, bf2f(f0), acc);
        acc = fmaf(p1, bf2f(f1), acc);
        acc = fmaf(p2, bf2f(f2), acc);
        acc = fmaf(p3, bf2f(f3), acc);
        dsum += (p0 + p1) + (p2 + p3);
    }
    for (; e < e1; ++e) {
        int s0 = csr_src[e];
        float e0 = as_[s0] + ad;
        e0 = e0 > 0.f ? e0 : LRELU_SLOPE * e0;
        float p0 = __expf(e0);
        acc = fmaf(p0, bf2f(h2[(size_t)s0 * 64 + lane]), acc);
        dsum += p0;
    }
    float v = acc / (dsum + 1e-16f) + b2[lane];
    v = v > 0.f ? v : expm1f(v);
    hout[(size_t)w * 64 + lane] = v;
    float sc = v * Wsv[lane];
    #pragma unroll
    for (int off = 32; off; off >>= 1) sc += __shfl_down(sc, off);
    if (lane == 0) scores[w] = sc + bs[0];
}

// ---------------------------------------------------------------------------
extern "C" void kernel_launch(void* const* d_in, const int* in_sizes, int n_in,
                              void* d_out, int out_size, void* d_ws, size_t ws_size,
                              hipStream_t stream)
{
    const float* x    = (const float*)d_in[0];
    const int*   ei   = (const int*)d_in[1];
    const float* W1   = (const float*)d_in[2];
    const float* as1w = (const float*)d_in[3];
    const float* ad1w = (const float*)d_in[4];
    const float* b1   = (const float*)d_in[5];
    const float* W2   = (const float*)d_in[6];
    const float* as2w = (const float*)d_in[7];
    const float* ad2w = (const float*)d_in[8];
    const float* b2   = (const float*)d_in[9];
    const float* Ws   = (const float*)d_in[10];
    const float* bs   = (const float*)d_in[11];

    const int N  = in_sizes[0] / 128;   // 50000
    const int E  = in_sizes[1] / 2;     // 800000
    const int* esrc = ei;
    const int* edst = ei + E;

    // ---- workspace layout (16B-aligned chunks) ----
    ushort* h1bf  = (ushort*)d_ws;                       // N*256 bf16
    ushort* hl1bf = h1bf + (size_t)N * 256;              // N*256 bf16
    ushort* h2bf  = hl1bf + (size_t)N * 256;             // N*64 bf16
    ushort* xbf   = h2bf + (size_t)N * 64;               // N*128 bf16
    ushort* bfr1  = xbf + (size_t)N * 128;               // 32768
    ushort* bfr2  = bfr1 + 32768;                        // 16384
    float*  as1   = (float*)(bfr2 + 16384);              // N*4
    float*  ad1   = as1 + (size_t)N * 4;                 // N*4
    float*  as2   = ad1 + (size_t)N * 4;                 // N
    float*  ad2   = as2 + N;                             // N
    int*    deg    = (int*)(ad2 + N);                    // N
    int*    order  = deg + N;                            // E
    int*    rowptr = order + E;                          // N+1 (+pad)
    int*    csr_src= rowptr + N + 4;                     // E

    float* hout   = (float*)d_out;                       // N*64
    float* scores = hout + (size_t)N * 64;               // N

    // ---------------- K0: zero deg ----------------
    hipMemsetAsync(deg, 0, (size_t)N * sizeof(int), stream);

    // ---------------- K1: hist(+order) + conv + prefrags ----------------
    const int nconv4 = N * 128 / 4;                      // 1,600,000
    const int nfrag  = 16 * 4 * 64 + 4 * 8 * 64;         // 6,144
    const int nhist  = (E + 3) / 4;                      // 200,000
    fused_front<<<(nconv4 + nfrag + nhist + 255) / 256, 256, 0, stream>>>(
        x, xbf, W1, W2, bfr1, bfr2, edst, deg, order, nconv4, E);

    // ---------------- K2: rowptr scan ----------------
    scan_rowptr<<<1, 1024, 0, stream>>>(deg, rowptr, N);

    // ---------------- K3: gemm1 + atomic-free scatter ----------------
    const int gemmBlocks    = (N / 16 + 3) / 4;          // 782
    const int scatterBlocks = (E + 255) / 256;           // 3125
    scatter_gemm1<<<gemmBlocks + scatterBlocks, 256, 0, stream>>>(
        xbf, bfr1, h1bf, as1w, ad1w, as1, ad1, N, gemmBlocks,
        esrc, edst, rowptr, order, csr_src, E);

    // ---------------- K4: agg1 ----------------
    aggregate_l1<<<((size_t)N * 64 + 255) / 256, 256, 0, stream>>>(
        rowptr, csr_src, h1bf, as1, ad1, b1, hl1bf, N);

    // ---------------- K5: gemm2 ----------------
    gemm_mfma<4, 8, 1><<<(N / 16 + 3) / 4, 256, 0, stream>>>(
        hl1bf, bfr2, h2bf, as2w, ad2w, as2, ad2, N);

    // ---------------- K6: agg2 + scoring head ----------------
    aggregate_l2<<<((size_t)N * 64 + 255) / 256, 256, 0, stream>>>(
        rowptr, csr_src, h2bf, as2, ad2, b2, Ws, bs, hout, scores, N);
}